// Round 1
// baseline (4381.015 us; speedup 1.0000x reference)
//
#include <hip/hip_runtime.h>
#include <hip/hip_bf16.h>
#include <math.h>

// QRNN quantum-circuit simulator, 16 qubits, B=256, T=32.
// State layout: float2 S[b][s], s = h*256 + l ; qubit j<8 <-> bit j of l (data
// qubits), qubit 8+k <-> bit k of h. Per timestep:
//   pass A: 8 fused gates V_j = G_j * Ry(arccos x_bt) on low bits (register/shfl)
//           (also multiplies the deferred low-diagonal phase of the previous step)
//   pass B: 8 gates G_{8+k} on high bits (LDS transpose), then high+cross RZZ
//           diagonal. Final pass B instead computes sum |psi|^2 * Q(l) -> out.

#define DEV static __device__ __forceinline__

DEV float2 cmul(float2 a, float2 b){ return make_float2(a.x*b.x - a.y*b.y, a.x*b.y + a.y*b.x); }
DEV float2 cadd(float2 a, float2 b){ return make_float2(a.x+b.x, a.y+b.y); }
DEV float2 cscale(float s, float2 a){ return make_float2(s*a.x, s*a.y); }
// u0*a + u1*b (complex)
DEV float2 cfma2(float2 u0, float2 a, float2 u1, float2 b){
  return make_float2(u0.x*a.x - u0.y*a.y + u1.x*b.x - u1.y*b.y,
                     u0.x*a.y + u0.y*a.x + u1.x*b.y + u1.y*b.x);
}
DEV float2 shx(float2 v, int m){
  return make_float2(__shfl_xor(v.x, m, 64), __shfl_xor(v.y, m, 64));
}
DEV void gpair(float2 &A, float2 &B, float2 u00, float2 u01, float2 u10, float2 u11){
  float2 na = cfma2(u00, A, u01, B);
  float2 nb = cfma2(u10, A, u11, B);
  A = na; B = nb;
}

// Apply 8 single-qubit gates to a 256-amplitude slice held by one wave.
// Local 8-bit index n: bit0 and bit7 are in-thread, bits 1..6 = lane bits 0..5.
// a0: n=2L, a1: n=2L+1, a2: n=128+2L, a3: n=129+2L.
// gm[q*4 + (2r+c)] = matrix for the gate acting on local bit q.
DEV void apply8(float2 &a0, float2 &a1, float2 &a2, float2 &a3, int lane,
                const float2* __restrict__ gm){
  gpair(a0,a1, gm[0],gm[1],gm[2],gm[3]);        // bit 0
  gpair(a2,a3, gm[0],gm[1],gm[2],gm[3]);
  #pragma unroll
  for (int k=1;k<=6;k++){                        // bits 1..6 cross-lane
    const int m = 1<<(k-1);
    const bool hb = (lane>>(k-1)) & 1;
    float2 u00=gm[4*k+0], u01=gm[4*k+1], u10=gm[4*k+2], u11=gm[4*k+3];
    float2 cA = hb? u11:u00;   // coefficient of own amp
    float2 cP = hb? u10:u01;   // coefficient of partner amp
    a0 = cfma2(cA,a0,cP,shx(a0,m));
    a1 = cfma2(cA,a1,cP,shx(a1,m));
    a2 = cfma2(cA,a2,cP,shx(a2,m));
    a3 = cfma2(cA,a3,cP,shx(a3,m));
  }
  gpair(a0,a2, gm[28],gm[29],gm[30],gm[31]);    // bit 7
  gpair(a1,a3, gm[28],gm[29],gm[30],gm[31]);
}

// One block, 256 threads. Precomputes fused gates G_j, the low-diagonal table
// PHL[256], the high-diagonal tables PHB[4][256], and inits out[b]=b_out.
__global__ __launch_bounds__(256) void k_setup(
    const float* __restrict__ w, const float* __restrict__ b_out,
    float* __restrict__ out, float2* __restrict__ G,
    float2* __restrict__ PHL, float2* __restrict__ PHB){
  int tid = threadIdx.x;
  if (tid < 16){
    int j = tid;
    float a0 = w[j*4+0], a1 = w[j*4+1], a2 = w[j*4+2];
    float c0 = cosf(0.5f*a0), s0 = sinf(0.5f*a0);
    float c1 = cosf(0.5f*a1), s1 = sinf(0.5f*a1);
    float c2 = cosf(0.5f*a2), s2 = sinf(0.5f*a2);
    // M = RZ(a1)*RX(a0)
    float2 m00 = make_float2( c0*c1, -c0*s1);
    float2 m01 = make_float2(-s0*s1, -s0*c1);
    float2 m10 = make_float2( s0*s1, -s0*c1);
    float2 m11 = make_float2( c0*c1,  c0*s1);
    float2 mi2 = make_float2(0.f, -s2);      // -i*sin(a2/2)
    // G = RX(a2)*M
    G[j*4+0] = cadd(cscale(c2,m00), cmul(mi2,m10));
    G[j*4+1] = cadd(cscale(c2,m01), cmul(mi2,m11));
    G[j*4+2] = cadd(cmul(mi2,m00), cscale(c2,m10));
    G[j*4+3] = cadd(cmul(mi2,m01), cscale(c2,m11));
  }
  { // PHL[l]: edges (0,1)..(6,7), weight w[j+1,3]
    int l = tid; float phi = 0.f;
    for (int j=0;j<7;j++){
      float v = w[(j+1)*4+3];
      int u = ((l>>j)^(l>>(j+1)))&1;
      phi += -0.5f*v*(1.f-2.f*(float)u);
    }
    PHL[l] = make_float2(cosf(phi), sinf(phi));
  }
  // PHB[c][h]: edges (8,9)..(14,15) + cross (7,8) [w8] and (15,0) [w0];
  // c encodes (bit0(l), bit7(l)).
  for (int c=0;c<4;c++){
    int h = tid;
    float z0 = 1.f-2.f*(float)(c&1);
    float z7 = 1.f-2.f*(float)((c>>1)&1);
    float phi = 0.f;
    for (int k=0;k<7;k++){
      float v = w[(9+k)*4+3];
      int u = ((h>>k)^(h>>(k+1)))&1;
      phi += -0.5f*v*(1.f-2.f*(float)u);
    }
    phi += -0.5f*w[8*4+3]*z7*(1.f-2.f*(float)(h&1));
    phi += -0.5f*w[0*4+3]*(1.f-2.f*(float)((h>>7)&1))*z0;
    PHB[c*256+h] = make_float2(cosf(phi), sinf(phi));
  }
  out[tid] = b_out[0];   // out_size == 256
}

// Low-bit pass. grid = 256 b * 16 tiles; 4 waves/block, 4 h-blocks per wave.
template<bool INIT>
__global__ __launch_bounds__(256) void k_passA(
    const float* __restrict__ x, const float2* __restrict__ G,
    const float2* __restrict__ PHL, float2* __restrict__ S, int t){
  const int b    = blockIdx.x >> 4;
  const int tile = blockIdx.x & 15;
  const int lane = threadIdx.x & 63;
  const int wv   = threadIdx.x >> 6;
  __shared__ float2 V[32];                     // 8 fused V_j gates
  if (threadIdx.x < 8){
    int j = threadIdx.x;
    float xv = x[b*32 + t];
    float c = sqrtf(0.5f*(1.f+xv));            // cos(arccos(x)/2)
    float s = sqrtf(0.5f*(1.f-xv));            // sin(arccos(x)/2)
    float2 g00=G[j*4+0], g01=G[j*4+1], g10=G[j*4+2], g11=G[j*4+3];
    V[j*4+0] = cadd(cscale( c,g00), cscale(s,g01));   // V = G * Ry
    V[j*4+1] = cadd(cscale(-s,g00), cscale(c,g01));
    V[j*4+2] = cadd(cscale( c,g10), cscale(s,g11));
    V[j*4+3] = cadd(cscale(-s,g10), cscale(c,g11));
  }
  __syncthreads();
  #pragma unroll 1
  for (int it=0; it<4; ++it){
    const int hb = tile*16 + wv*4 + it;
    float2* blk = S + (((size_t)b)<<16) + (size_t)hb*256;
    float2 a0,a1,a2,a3;
    if (INIT){
      if (hb == 0){   // product state: amp(l) = prod_j Vcol0[bit_j(l)]
        float2 amp;
        int l0 = 2*lane;
        amp = make_float2(1.f,0.f);
        #pragma unroll
        for (int j=0;j<8;j++) amp = cmul(amp, V[j*4 + ((((l0+0)>>j)&1)?2:0)]);
        a0 = amp;
        amp = make_float2(1.f,0.f);
        #pragma unroll
        for (int j=0;j<8;j++) amp = cmul(amp, V[j*4 + ((((l0+1)>>j)&1)?2:0)]);
        a1 = amp;
        amp = make_float2(1.f,0.f);
        #pragma unroll
        for (int j=0;j<8;j++) amp = cmul(amp, V[j*4 + ((((l0+128)>>j)&1)?2:0)]);
        a2 = amp;
        amp = make_float2(1.f,0.f);
        #pragma unroll
        for (int j=0;j<8;j++) amp = cmul(amp, V[j*4 + ((((l0+129)>>j)&1)?2:0)]);
        a3 = amp;
      } else {
        a0=a1=a2=a3=make_float2(0.f,0.f);
      }
    } else {
      const float4* p4 = (const float4*)blk;
      float4 lo = p4[lane];
      float4 hi = p4[64+lane];
      a0 = make_float2(lo.x,lo.y); a1 = make_float2(lo.z,lo.w);
      a2 = make_float2(hi.x,hi.y); a3 = make_float2(hi.z,hi.w);
      // deferred low-diagonal RZZ phase from the previous step
      const float4* q4 = (const float4*)PHL;
      float4 plo = q4[lane];
      float4 phi4 = q4[64+lane];
      a0 = cmul(a0, make_float2(plo.x, plo.y));
      a1 = cmul(a1, make_float2(plo.z, plo.w));
      a2 = cmul(a2, make_float2(phi4.x, phi4.y));
      a3 = cmul(a3, make_float2(phi4.z, phi4.w));
      apply8(a0,a1,a2,a3,lane,V);
    }
    float4* o4 = (float4*)blk;
    o4[lane]    = make_float4(a0.x,a0.y,a1.x,a1.y);
    o4[64+lane] = make_float4(a2.x,a2.y,a3.x,a3.y);
  }
}

// High-bit pass. grid = 256 b * 32 l-tiles (8 l each); LDS transpose.
template<bool FINAL>
__global__ __launch_bounds__(256) void k_passB(
    const float2* __restrict__ G, const float2* __restrict__ PHB,
    const float* __restrict__ w_out, float2* __restrict__ S,
    float* __restrict__ out){
  const int b  = blockIdx.x >> 5;
  const int lt = blockIdx.x & 31;
  const int l0 = lt*8;
  const int tid  = threadIdx.x;
  const int lane = tid & 63;
  const int wv   = tid >> 6;
  __shared__ float2 lds[8*258];   // column dl at [dl*258 .. dl*258+256), pad 2
  __shared__ float red[4];
  const size_t base = (((size_t)b)<<16) + l0;
  #pragma unroll
  for (int k=0;k<8;k++){          // stage in (coalesced 64B segments)
    int e = k*256 + tid;
    int dl = e & 7, h = e >> 3;
    lds[dl*258 + h] = S[base + (size_t)h*256 + dl];
  }
  __syncthreads();
  float acc = 0.f;
  #pragma unroll 1
  for (int cc=0;cc<2;cc++){       // each wave owns 2 columns
    const int dl = wv*2 + cc;
    float2* col = lds + dl*258;
    float4 lo = *(const float4*)(col + 2*lane);
    float4 hi = *(const float4*)(col + 128 + 2*lane);
    float2 a0 = make_float2(lo.x,lo.y), a1 = make_float2(lo.z,lo.w);
    float2 a2 = make_float2(hi.x,hi.y), a3 = make_float2(hi.z,hi.w);
    apply8(a0,a1,a2,a3,lane, G + 32);          // gates on qubits 8..15
    if (!FINAL){
      const int c = (dl & 1) | (((l0>>7)&1)<<1);
      const float4* r4 = (const float4*)(PHB + c*256);
      float4 plo = r4[lane];
      float4 phi4 = r4[64+lane];
      a0 = cmul(a0, make_float2(plo.x, plo.y));
      a1 = cmul(a1, make_float2(plo.z, plo.w));
      a2 = cmul(a2, make_float2(phi4.x, phi4.y));
      a3 = cmul(a3, make_float2(phi4.z, phi4.w));
      *(float4*)(col + 2*lane)       = make_float4(a0.x,a0.y,a1.x,a1.y);
      *(float4*)(col + 128 + 2*lane) = make_float4(a2.x,a2.y,a3.x,a3.y);
    } else {
      // fused expectation: sum_s |psi_s|^2 * Q(l), Q = sum_j w_out[j]*(1-2 bit_j)
      const int l = l0 + dl;
      float q = 0.f;
      #pragma unroll
      for (int j=0;j<8;j++) q += w_out[j] * (1.f - 2.f*(float)((l>>j)&1));
      float ss = a0.x*a0.x+a0.y*a0.y + a1.x*a1.x+a1.y*a1.y
               + a2.x*a2.x+a2.y*a2.y + a3.x*a3.x+a3.y*a3.y;
      acc += q*ss;
    }
  }
  if (!FINAL){
    __syncthreads();
    #pragma unroll
    for (int k=0;k<8;k++){        // stage out
      int e = k*256 + tid;
      int dl = e & 7, h = e >> 3;
      S[base + (size_t)h*256 + dl] = lds[dl*258 + h];
    }
  } else {
    #pragma unroll
    for (int m=1;m<64;m<<=1) acc += __shfl_xor(acc, m, 64);
    if (lane==0) red[wv] = acc;
    __syncthreads();
    if (tid==0) atomicAdd(out + b, red[0]+red[1]+red[2]+red[3]);
  }
}

extern "C" void kernel_launch(void* const* d_in, const int* in_sizes, int n_in,
                              void* d_out, int out_size, void* d_ws, size_t ws_size,
                              hipStream_t stream){
  const float* x     = (const float*)d_in[0];   // [256,32]
  const float* w     = (const float*)d_in[1];   // [16,4]
  const float* w_out = (const float*)d_in[2];   // [1,8]
  const float* b_out = (const float*)d_in[3];   // [1]
  float* out = (float*)d_out;                   // [256]

  const size_t S_BYTES = (size_t)256 * 65536 * sizeof(float2);  // 128 MB
  const size_t NEED = S_BYTES + 512 + 2048 + 8192;
  if (ws_size < NEED) return;  // workspace too small; fail loudly via validation

  float2* S   = (float2*)d_ws;
  float2* G   = (float2*)((char*)d_ws + S_BYTES);  // 64 entries
  float2* PHL = G + 64;                            // 256 entries
  float2* PHB = PHL + 256;                         // 1024 entries

  k_setup<<<1,256,0,stream>>>(w, b_out, out, G, PHL, PHB);
  for (int t=0;t<32;t++){
    if (t==0) k_passA<true ><<<4096,256,0,stream>>>(x, G, PHL, S, t);
    else      k_passA<false><<<4096,256,0,stream>>>(x, G, PHL, S, t);
    if (t<31) k_passB<false><<<8192,256,0,stream>>>(G, PHB, w_out, S, out);
    else      k_passB<true ><<<8192,256,0,stream>>>(G, PHB, w_out, S, out);
  }
}

// Round 2
// 4060.225 us; speedup vs baseline: 1.0790x; 1.0790x over previous
//
#include <hip/hip_runtime.h>
#include <hip/hip_bf16.h>
#include <math.h>

// QRNN quantum-circuit simulator, 16 qubits, B=256, T=32.
// State layout (R): float2 S[b][s], s = h*256 + l ; qubit j<8 <-> bit j of l
// (data qubits), qubit 8+k <-> bit k of h. Per timestep:
//   pass A: 8 fused gates V_j = G_j * Ry(arccos x_bt) on low bits
//           (pure streaming: contiguous read, registers+shfl, contiguous write)
//   pass B: 8 gates G_{8+k} on high bits (LDS transpose, 16-l tiles, float4
//           128B segments both directions), then the FULL RZZ diagonal
//           (low part PHL[l] is wave-uniform per column; high+cross part
//           PHB[c][h] per lane). Final pass B computes sum |psi|^2 Q(l) -> out
//           and skips the diagonal (phases don't affect probabilities).

#define DEV static __device__ __forceinline__

DEV float2 cmul(float2 a, float2 b){ return make_float2(a.x*b.x - a.y*b.y, a.x*b.y + a.y*b.x); }
DEV float2 cadd(float2 a, float2 b){ return make_float2(a.x+b.x, a.y+b.y); }
DEV float2 cscale(float s, float2 a){ return make_float2(s*a.x, s*a.y); }
// u0*a + u1*b (complex)
DEV float2 cfma2(float2 u0, float2 a, float2 u1, float2 b){
  return make_float2(u0.x*a.x - u0.y*a.y + u1.x*b.x - u1.y*b.y,
                     u0.x*a.y + u0.y*a.x + u1.x*b.y + u1.y*b.x);
}
DEV float2 shx(float2 v, int m){
  return make_float2(__shfl_xor(v.x, m, 64), __shfl_xor(v.y, m, 64));
}
DEV void gpair(float2 &A, float2 &B, float2 u00, float2 u01, float2 u10, float2 u11){
  float2 na = cfma2(u00, A, u01, B);
  float2 nb = cfma2(u10, A, u11, B);
  A = na; B = nb;
}

// Apply 8 single-qubit gates to a 256-amplitude slice held by one wave.
// Local 8-bit index n: bit0 and bit7 are in-thread, bits 1..6 = lane bits 0..5.
// a0: n=2L, a1: n=2L+1, a2: n=128+2L, a3: n=129+2L.
// gm[q*4 + (2r+c)] = matrix for the gate acting on local bit q.
DEV void apply8(float2 &a0, float2 &a1, float2 &a2, float2 &a3, int lane,
                const float2* __restrict__ gm){
  gpair(a0,a1, gm[0],gm[1],gm[2],gm[3]);        // bit 0
  gpair(a2,a3, gm[0],gm[1],gm[2],gm[3]);
  #pragma unroll
  for (int k=1;k<=6;k++){                        // bits 1..6 cross-lane
    const int m = 1<<(k-1);
    const bool hb = (lane>>(k-1)) & 1;
    float2 u00=gm[4*k+0], u01=gm[4*k+1], u10=gm[4*k+2], u11=gm[4*k+3];
    float2 cA = hb? u11:u00;   // coefficient of own amp
    float2 cP = hb? u10:u01;   // coefficient of partner amp
    a0 = cfma2(cA,a0,cP,shx(a0,m));
    a1 = cfma2(cA,a1,cP,shx(a1,m));
    a2 = cfma2(cA,a2,cP,shx(a2,m));
    a3 = cfma2(cA,a3,cP,shx(a3,m));
  }
  gpair(a0,a2, gm[28],gm[29],gm[30],gm[31]);    // bit 7
  gpair(a1,a3, gm[28],gm[29],gm[30],gm[31]);
}

// One block, 256 threads. Precomputes fused gates G_j, the low-diagonal table
// PHL[256], the high-diagonal tables PHB[4][256], and inits out[b]=b_out.
__global__ __launch_bounds__(256) void k_setup(
    const float* __restrict__ w, const float* __restrict__ b_out,
    float* __restrict__ out, float2* __restrict__ G,
    float2* __restrict__ PHL, float2* __restrict__ PHB){
  int tid = threadIdx.x;
  if (tid < 16){
    int j = tid;
    float a0 = w[j*4+0], a1 = w[j*4+1], a2 = w[j*4+2];
    float c0 = cosf(0.5f*a0), s0 = sinf(0.5f*a0);
    float c1 = cosf(0.5f*a1), s1 = sinf(0.5f*a1);
    float c2 = cosf(0.5f*a2), s2 = sinf(0.5f*a2);
    // M = RZ(a1)*RX(a0)
    float2 m00 = make_float2( c0*c1, -c0*s1);
    float2 m01 = make_float2(-s0*s1, -s0*c1);
    float2 m10 = make_float2( s0*s1, -s0*c1);
    float2 m11 = make_float2( c0*c1,  c0*s1);
    float2 mi2 = make_float2(0.f, -s2);      // -i*sin(a2/2)
    // G = RX(a2)*M
    G[j*4+0] = cadd(cscale(c2,m00), cmul(mi2,m10));
    G[j*4+1] = cadd(cscale(c2,m01), cmul(mi2,m11));
    G[j*4+2] = cadd(cmul(mi2,m00), cscale(c2,m10));
    G[j*4+3] = cadd(cmul(mi2,m01), cscale(c2,m11));
  }
  { // PHL[l]: edges (0,1)..(6,7), weight w[j+1,3]
    int l = tid; float phi = 0.f;
    for (int j=0;j<7;j++){
      float v = w[(j+1)*4+3];
      int u = ((l>>j)^(l>>(j+1)))&1;
      phi += -0.5f*v*(1.f-2.f*(float)u);
    }
    PHL[l] = make_float2(cosf(phi), sinf(phi));
  }
  // PHB[c][h]: edges (8,9)..(14,15) + cross (7,8) [w8] and (15,0) [w0];
  // c encodes (bit0(l), bit7(l)).
  for (int c=0;c<4;c++){
    int h = tid;
    float z0 = 1.f-2.f*(float)(c&1);
    float z7 = 1.f-2.f*(float)((c>>1)&1);
    float phi = 0.f;
    for (int k=0;k<7;k++){
      float v = w[(9+k)*4+3];
      int u = ((h>>k)^(h>>(k+1)))&1;
      phi += -0.5f*v*(1.f-2.f*(float)u);
    }
    phi += -0.5f*w[8*4+3]*z7*(1.f-2.f*(float)(h&1));
    phi += -0.5f*w[0*4+3]*(1.f-2.f*(float)((h>>7)&1))*z0;
    PHB[c*256+h] = make_float2(cosf(phi), sinf(phi));
  }
  out[tid] = b_out[0];   // out_size == 256
}

// Low-bit pass. grid = 256 b * 16 tiles; 4 waves/block, 4 h-blocks per wave.
// Pure streaming (no diagonal here; the full diagonal lives in pass B).
template<bool INIT>
__global__ __launch_bounds__(256) void k_passA(
    const float* __restrict__ x, const float2* __restrict__ G,
    float2* __restrict__ S, int t){
  const int b    = blockIdx.x >> 4;
  const int tile = blockIdx.x & 15;
  const int lane = threadIdx.x & 63;
  const int wv   = threadIdx.x >> 6;
  __shared__ float2 V[32];                     // 8 fused V_j gates
  if (threadIdx.x < 8){
    int j = threadIdx.x;
    float xv = x[b*32 + t];
    float c = sqrtf(0.5f*(1.f+xv));            // cos(arccos(x)/2)
    float s = sqrtf(0.5f*(1.f-xv));            // sin(arccos(x)/2)
    float2 g00=G[j*4+0], g01=G[j*4+1], g10=G[j*4+2], g11=G[j*4+3];
    V[j*4+0] = cadd(cscale( c,g00), cscale(s,g01));   // V = G * Ry
    V[j*4+1] = cadd(cscale(-s,g00), cscale(c,g01));
    V[j*4+2] = cadd(cscale( c,g10), cscale(s,g11));
    V[j*4+3] = cadd(cscale(-s,g10), cscale(c,g11));
  }
  __syncthreads();
  #pragma unroll 1
  for (int it=0; it<4; ++it){
    const int hb = tile*16 + wv*4 + it;
    float2* blk = S + (((size_t)b)<<16) + (size_t)hb*256;
    float2 a0,a1,a2,a3;
    if (INIT){
      if (hb == 0){   // product state: amp(l) = prod_j Vcol0[bit_j(l)]
        float2 amp;
        int l0 = 2*lane;
        amp = make_float2(1.f,0.f);
        #pragma unroll
        for (int j=0;j<8;j++) amp = cmul(amp, V[j*4 + ((((l0+0)>>j)&1)?2:0)]);
        a0 = amp;
        amp = make_float2(1.f,0.f);
        #pragma unroll
        for (int j=0;j<8;j++) amp = cmul(amp, V[j*4 + ((((l0+1)>>j)&1)?2:0)]);
        a1 = amp;
        amp = make_float2(1.f,0.f);
        #pragma unroll
        for (int j=0;j<8;j++) amp = cmul(amp, V[j*4 + ((((l0+128)>>j)&1)?2:0)]);
        a2 = amp;
        amp = make_float2(1.f,0.f);
        #pragma unroll
        for (int j=0;j<8;j++) amp = cmul(amp, V[j*4 + ((((l0+129)>>j)&1)?2:0)]);
        a3 = amp;
      } else {
        a0=a1=a2=a3=make_float2(0.f,0.f);
      }
    } else {
      const float4* p4 = (const float4*)blk;
      float4 lo = p4[lane];
      float4 hi = p4[64+lane];
      a0 = make_float2(lo.x,lo.y); a1 = make_float2(lo.z,lo.w);
      a2 = make_float2(hi.x,hi.y); a3 = make_float2(hi.z,hi.w);
      apply8(a0,a1,a2,a3,lane,V);
    }
    float4* o4 = (float4*)blk;
    o4[lane]    = make_float4(a0.x,a0.y,a1.x,a1.y);
    o4[64+lane] = make_float4(a2.x,a2.y,a3.x,a3.y);
  }
}

// High-bit pass. grid = 256 b * 16 l-tiles (16 l each); LDS transpose.
// Staging/writeback use float4 (full 128B cache-line segments). LDS layout
// [dl][258 float2]: column b128 reads conflict-free; staging b64 writes 2-way
// (free). Applies high gates then the FULL RZZ diagonal PHL[l]*PHB[c][h].
template<bool FINAL>
__global__ __launch_bounds__(256) void k_passB(
    const float2* __restrict__ G, const float2* __restrict__ PHL,
    const float2* __restrict__ PHB, const float* __restrict__ w_out,
    float2* __restrict__ S, float* __restrict__ out){
  const int b  = blockIdx.x >> 4;
  const int lt = blockIdx.x & 15;
  const int l0 = lt*16;
  const int tid  = threadIdx.x;
  const int lane = tid & 63;
  const int wv   = tid >> 6;
  __shared__ float2 lds[16*258];   // column dl at [dl*258 .. dl*258+256)
  __shared__ float red[4];
  float4* Sb4 = (float4*)(S + (((size_t)b)<<16));
  const int colbase = l0 >> 1;     // float4 index offset of this l-tile
  #pragma unroll
  for (int k=0;k<8;k++){           // stage in: 128B segments per 8 lanes
    int idx = k*256 + tid;
    int q = idx & 7, h = idx >> 3;
    float4 v = Sb4[h*128 + colbase + q];
    int dl2 = q*2;
    lds[dl2*258 + h]     = make_float2(v.x, v.y);
    lds[(dl2+1)*258 + h] = make_float2(v.z, v.w);
  }
  __syncthreads();
  float acc = 0.f;
  #pragma unroll 1
  for (int cc=0;cc<4;cc++){        // each wave owns 4 columns
    const int dl = wv*4 + cc;
    float2* col = lds + dl*258;
    float4 lo = *(const float4*)(col + 2*lane);
    float4 hi = *(const float4*)(col + 128 + 2*lane);
    float2 a0 = make_float2(lo.x,lo.y), a1 = make_float2(lo.z,lo.w);
    float2 a2 = make_float2(hi.x,hi.y), a3 = make_float2(hi.z,hi.w);
    apply8(a0,a1,a2,a3,lane, G + 32);          // gates on qubits 8..15
    if (!FINAL){
      const int l = l0 + dl;
      const int c = (l & 1) | (((l >> 7) & 1) << 1);
      const float2 phl = PHL[l];               // wave-uniform scalar
      const float4* r4 = (const float4*)(PHB + c*256);
      float4 plo = r4[lane];
      float4 phi4 = r4[64+lane];
      a0 = cmul(a0, cmul(phl, make_float2(plo.x, plo.y)));
      a1 = cmul(a1, cmul(phl, make_float2(plo.z, plo.w)));
      a2 = cmul(a2, cmul(phl, make_float2(phi4.x, phi4.y)));
      a3 = cmul(a3, cmul(phl, make_float2(phi4.z, phi4.w)));
      *(float4*)(col + 2*lane)       = make_float4(a0.x,a0.y,a1.x,a1.y);
      *(float4*)(col + 128 + 2*lane) = make_float4(a2.x,a2.y,a3.x,a3.y);
    } else {
      // fused expectation: sum_s |psi_s|^2 * Q(l); diagonal skipped (|.|^2)
      const int l = l0 + dl;
      float q = 0.f;
      #pragma unroll
      for (int j=0;j<8;j++) q += w_out[j] * (1.f - 2.f*(float)((l>>j)&1));
      float ss = a0.x*a0.x+a0.y*a0.y + a1.x*a1.x+a1.y*a1.y
               + a2.x*a2.x+a2.y*a2.y + a3.x*a3.x+a3.y*a3.y;
      acc += q*ss;
    }
  }
  if (!FINAL){
    __syncthreads();
    #pragma unroll
    for (int k=0;k<8;k++){         // stage out: mirror of stage in
      int idx = k*256 + tid;
      int q = idx & 7, h = idx >> 3;
      int dl2 = q*2;
      float2 v0 = lds[dl2*258 + h];
      float2 v1 = lds[(dl2+1)*258 + h];
      Sb4[h*128 + colbase + q] = make_float4(v0.x, v0.y, v1.x, v1.y);
    }
  } else {
    #pragma unroll
    for (int m=1;m<64;m<<=1) acc += __shfl_xor(acc, m, 64);
    if (lane==0) red[wv] = acc;
    __syncthreads();
    if (tid==0) atomicAdd(out + b, red[0]+red[1]+red[2]+red[3]);
  }
}

extern "C" void kernel_launch(void* const* d_in, const int* in_sizes, int n_in,
                              void* d_out, int out_size, void* d_ws, size_t ws_size,
                              hipStream_t stream){
  const float* x     = (const float*)d_in[0];   // [256,32]
  const float* w     = (const float*)d_in[1];   // [16,4]
  const float* w_out = (const float*)d_in[2];   // [1,8]
  const float* b_out = (const float*)d_in[3];   // [1]
  float* out = (float*)d_out;                   // [256]

  const size_t S_BYTES = (size_t)256 * 65536 * sizeof(float2);  // 128 MB
  const size_t NEED = S_BYTES + 512 + 2048 + 8192;
  if (ws_size < NEED) return;  // workspace too small; fail loudly via validation

  float2* S   = (float2*)d_ws;
  float2* G   = (float2*)((char*)d_ws + S_BYTES);  // 64 entries
  float2* PHL = G + 64;                            // 256 entries
  float2* PHB = PHL + 256;                         // 1024 entries

  k_setup<<<1,256,0,stream>>>(w, b_out, out, G, PHL, PHB);
  for (int t=0;t<32;t++){
    if (t==0) k_passA<true ><<<4096,256,0,stream>>>(x, G, S, t);
    else      k_passA<false><<<4096,256,0,stream>>>(x, G, S, t);
    if (t<31) k_passB<false><<<4096,256,0,stream>>>(G, PHL, PHB, w_out, S, out);
    else      k_passB<true ><<<4096,256,0,stream>>>(G, PHL, PHB, w_out, S, out);
  }
}